// Round 1
// baseline (78.915 us; speedup 1.0000x reference)
//
#include <hip/hip_runtime.h>
#include <math.h>

constexpr int Bn = 512;      // batch
constexpr int Dn = 16384;    // priors
constexpr int BS = 512;      // block size (8 waves)

struct WS {
  double loc[Bn];
  double conf[Bn];
  double np[Bn];
};

__device__ __forceinline__ double blockReduceAddD(double v, double* sred) {
  int t = threadIdx.x;
  sred[t] = v;
  __syncthreads();
  for (int off = BS >> 1; off > 0; off >>= 1) {
    if (t < off) sred[t] += sred[t + off];
    __syncthreads();
  }
  double r = sred[0];
  __syncthreads();
  return r;
}

__global__ __launch_bounds__(BS) void multiloss_main(
    const float* __restrict__ loc_pred, const float* __restrict__ conf_pred,
    const float* __restrict__ targets, const float* __restrict__ default_bar,
    WS* __restrict__ ws)
{
  __shared__ float    s_lc[Dn];        // 64 KB
  __shared__ int      s_hist[2048];    // 8 KB (also reused for argmax reduce)
  __shared__ unsigned s_scan[BS];      // 2 KB
  __shared__ double   s_dred[BS];      // 4 KB
  __shared__ unsigned s_sel[2];
  __shared__ double   s_corr[2];
  __shared__ int      s_np;

  const int b = blockIdx.x;
  const int t = threadIdx.x;

  const float t0  = targets[b * 3 + 0];
  const float t1  = targets[b * 3 + 1];
  const int   lab = (int)targets[b * 3 + 2];

  const float* __restrict__ cpb = conf_pred + (size_t)b * Dn * 3;

  if (lab == 0) {
    // Whole row is background-positive: sum ce over all d, num_pos = D, no loc loss.
    float ce = 0.f;
    for (int d = t; d < Dn; d += BS) {
      const float* cp = cpb + d * 3;
      float c0 = cp[0], c1 = cp[1], c2 = cp[2];
      float m   = fmaxf(c0, fmaxf(c1, c2));
      float lse = m + logf(expf(c0 - m) + expf(c1 - m) + expf(c2 - m));
      ce += lse - c0;
    }
    double tot = blockReduceAddD((double)ce, s_dred);
    if (t == 0) { ws->loc[b] = 0.0; ws->conf[b] = tot; ws->np[b] = (double)Dn; }
    return;
  }

  const float m_c = (t0 + t1) * 0.5f;
  const float m_l = t1 - t0;

  float bestV = -1.f; int bestI = 0;
  int   nposL = 0;
  float cePosL = 0.f;
  float llocL  = 0.f;

  for (int d = t; d < Dn; d += BS) {
    float2 db = ((const float2*)default_bar)[d];
    float d_c = db.x, d_l = db.y;
    float d_s = d_c - d_l * 0.5f;
    float d_e = d_c + d_l * 0.5f;
    float inter = fminf(t1, d_e) - fmaxf(t0, d_s);
    inter = fmaxf(inter, 0.f);
    float uni = (t1 - t0) + (d_e - d_s) - inter;
    float ov  = inter / uni;

    const float* cp = cpb + d * 3;
    float c0 = cp[0], c1 = cp[1], c2 = cp[2];
    float m   = fmaxf(c0, fmaxf(c1, c2));
    float lse = m + logf(expf(c0 - m) + expf(c1 - m) + expf(c2 - m));

    if (ov > bestV) { bestV = ov; bestI = d; }  // ascending d -> first max kept

    float lcv;
    if (ov >= 0.5f) {
      nposL++;
      float cl = (lab == 1) ? c1 : c2;
      cePosL += lse - cl;
      float2 lp = ((const float2*)loc_pred)[(size_t)b * Dn + d];
      float pd0 = lp.x - (m_c - d_c) / d_l;
      float pd1 = lp.y - logf(m_l / d_l);
      float a0 = fabsf(pd0), a1 = fabsf(pd1);
      llocL += (a0 < 1.f ? 0.5f * pd0 * pd0 : a0 - 0.5f)
             + (a1 < 1.f ? 0.5f * pd1 * pd1 : a1 - 0.5f);
      lcv = 0.f;
    } else {
      lcv = lse - c0;
    }
    s_lc[d] = lcv;
  }

  // ---- argmax(ov) with first-index tie-break (reuse s_hist region) ----
  float* sv = (float*)s_hist;         // [0..BS)
  int*   si = (int*)(s_hist + BS);    // [BS..2BS)
  sv[t] = bestV; si[t] = bestI;
  __syncthreads();
  for (int off = BS >> 1; off > 0; off >>= 1) {
    if (t < off) {
      float v2 = sv[t + off]; int i2 = si[t + off];
      if (v2 > sv[t] || (v2 == sv[t] && i2 < si[t])) { sv[t] = v2; si[t] = i2; }
    }
    __syncthreads();
  }
  float bV = sv[0]; int bI = si[0];
  __syncthreads();

  double nposTot  = blockReduceAddD((double)nposL, s_dred);
  double cePosTot = blockReduceAddD((double)cePosL, s_dred);
  double llocTot  = blockReduceAddD((double)llocL, s_dred);
  int num_pos = (int)(nposTot + 0.5);

  // ---- best-prior correction (single element) ----
  if (t == 0) {
    double cc = 0.0, lcor = 0.0; int np2 = num_pos;
    if (bV < 0.5f) {
      int d = bI;
      const float* cp = cpb + d * 3;
      float c0 = cp[0], c1 = cp[1], c2 = cp[2];
      float m   = fmaxf(c0, fmaxf(c1, c2));
      float lse = m + logf(expf(c0 - m) + expf(c1 - m) + expf(c2 - m));
      float cl = (lab == 1) ? c1 : c2;
      cc = (double)(lse - cl);
      float2 db = ((const float2*)default_bar)[d];
      float2 lp = ((const float2*)loc_pred)[(size_t)b * Dn + d];
      float pd0 = lp.x - (m_c - db.x) / db.y;
      float pd1 = lp.y - logf(m_l / db.y);
      float a0 = fabsf(pd0), a1 = fabsf(pd1);
      lcor = (double)((a0 < 1.f ? 0.5f * pd0 * pd0 : a0 - 0.5f)
                    + (a1 < 1.f ? 0.5f * pd1 * pd1 : a1 - 0.5f));
      np2 += 1;
      s_lc[d] = 0.f;   // forced positive leaves the negative pool
    }
    s_corr[0] = cc; s_corr[1] = lcor; s_np = np2;
  }
  __syncthreads();
  int np = s_np;
  int k  = min(3 * np, Dn - 1);   // k >= 3 always

  // ---- radix select: k-th largest of s_lc (all values >= 0 -> uint-monotonic) ----
  // rounds: bits [31:21] (11b), [20:10] (11b), [9:0] (10b)
  unsigned prefix = 0;
  int K = k;
  for (int r = 0; r < 3; ++r) {
    for (int i = t; i < 2048; i += BS) s_hist[i] = 0;
    __syncthreads();
    for (int d = t; d < Dn; d += BS) {
      unsigned u = __float_as_uint(s_lc[d]);
      bool ok = (r == 0) || (r == 1 ? ((u >> 21) == prefix) : ((u >> 10) == prefix));
      if (ok) {
        unsigned bin = (r == 0) ? (u >> 21)
                     : (r == 1) ? ((u >> 10) & 0x7FFu)
                                : (u & 0x3FFu);
        atomicAdd(&s_hist[bin], 1);
      }
    }
    __syncthreads();
    int nb  = (r == 2) ? 1024 : 2048;
    int per = nb / BS;              // 2 or 4
    unsigned psum = 0;
    for (int j = 0; j < per; ++j) psum += (unsigned)s_hist[t * per + j];
    s_scan[t] = psum;
    __syncthreads();
    for (int off = 1; off < BS; off <<= 1) {
      unsigned v = (t + off < BS) ? s_scan[t + off] : 0u;
      __syncthreads();
      s_scan[t] += v;
      __syncthreads();
    }
    unsigned above = (t < BS - 1) ? s_scan[t + 1] : 0u;
    if (above < (unsigned)K && (unsigned)K <= above + psum) {
      unsigned cum = above;
      int found = 0;
      for (int j = per - 1; j >= 0; --j) {
        unsigned c = (unsigned)s_hist[t * per + j];
        if (cum + c >= (unsigned)K) { found = j; break; }
        cum += c;
      }
      s_sel[0] = (unsigned)(t * per + found);
      s_sel[1] = cum;
    }
    __syncthreads();
    unsigned selBin = s_sel[0];
    K -= (int)s_sel[1];
    prefix = (r == 0) ? selBin
           : (r == 1) ? ((prefix << 11) | selBin)
                      : ((prefix << 10) | selBin);
    __syncthreads();
  }
  const unsigned tb = prefix;           // bits of the k-th largest value

  // ---- final: sum of strictly-greater + boundary ties ----
  float    ssum = 0.f;
  unsigned scnt = 0;
  for (int d = t; d < Dn; d += BS) {
    float v = s_lc[d];
    if (__float_as_uint(v) > tb) { ssum += v; scnt++; }
  }
  double S = blockReduceAddD((double)ssum, s_dred);
  double C = blockReduceAddD((double)scnt, s_dred);

  if (t == 0) {
    double tval = (double)__uint_as_float(tb);
    double topk = S + ((double)k - C) * tval;
    ws->loc[b]  = llocTot + s_corr[1];
    ws->conf[b] = cePosTot + s_corr[0] + topk;
    ws->np[b]   = (double)s_np;
  }
}

__global__ __launch_bounds__(512) void multiloss_final(const WS* __restrict__ ws,
                                                       float* __restrict__ out) {
  __shared__ double s1[512], s2[512], s3[512];
  int t = threadIdx.x;
  s1[t] = ws->loc[t];
  s2[t] = ws->conf[t];
  s3[t] = ws->np[t];
  __syncthreads();
  for (int off = 256; off > 0; off >>= 1) {
    if (t < off) { s1[t] += s1[t + off]; s2[t] += s2[t + off]; s3[t] += s3[t + off]; }
    __syncthreads();
  }
  if (t == 0) {
    double N = s3[0];
    out[0] = (float)(s1[0] / N);
    out[1] = (float)(s2[0] / N);
  }
}

extern "C" void kernel_launch(void* const* d_in, const int* in_sizes, int n_in,
                              void* d_out, int out_size, void* d_ws, size_t ws_size,
                              hipStream_t stream) {
  const float* loc_pred    = (const float*)d_in[0];
  const float* conf_pred   = (const float*)d_in[1];
  const float* targets     = (const float*)d_in[2];
  const float* default_bar = (const float*)d_in[3];
  WS* ws = (WS*)d_ws;
  float* out = (float*)d_out;

  hipLaunchKernelGGL(multiloss_main, dim3(Bn), dim3(BS), 0, stream,
                     loc_pred, conf_pred, targets, default_bar, ws);
  hipLaunchKernelGGL(multiloss_final, dim3(1), dim3(512), 0, stream, ws, out);
}

// Round 2
// 74.230 us; speedup vs baseline: 1.0631x; 1.0631x over previous
//
#include <hip/hip_runtime.h>
#include <math.h>

constexpr int Bn = 512;      // batch
constexpr int Dn = 16384;    // priors
constexpr int BS = 512;      // select-kernel block size (8 waves)
constexpr int CHUNKS = 4;
constexpr int CPRI = Dn / CHUNKS;  // 4096 priors per chunk
constexpr int K1T = 256;           // stream-kernel threads

__device__ __forceinline__ float lse3(float a, float b, float c) {
  float m = fmaxf(a, fmaxf(b, c));
  return m + __logf(__expf(a - m) + __expf(b - m) + __expf(c - m));
}
__device__ __forceinline__ float sl1f(float x) {
  float a = fabsf(x);
  return a < 1.f ? 0.5f * x * x : a - 0.5f;
}

__device__ __forceinline__ double blockReduceAddD(double v, double* sred) {
  int t = threadIdx.x;
  sred[t] = v;
  __syncthreads();
  for (int off = BS >> 1; off > 0; off >>= 1) {
    if (t < off) sred[t] += sred[t + off];
    __syncthreads();
  }
  double r = sred[0];
  __syncthreads();
  return r;
}

// ============================ K1: streaming ============================
__global__ __launch_bounds__(K1T) void multiloss_stream(
    const float* __restrict__ loc_pred, const float* __restrict__ conf_pred,
    const float* __restrict__ targets, const float* __restrict__ default_bar,
    float* __restrict__ lc,
    float* __restrict__ pce, float* __restrict__ plloc, int* __restrict__ pnpos,
    float* __restrict__ pbv, int* __restrict__ pbi)
{
  const int bid = blockIdx.x;
  const int b = bid >> 2, c = bid & 3;
  const int t = threadIdx.x;

  const float t0 = targets[b * 3 + 0];
  const float t1 = targets[b * 3 + 1];
  const int   lab = (int)targets[b * 3 + 2];

  const float4* __restrict__ cp4  = (const float4*)(conf_pred + (size_t)b * Dn * 3);
  const float4* __restrict__ bar4 = (const float4*)default_bar;
  const int qbase = (c * CPRI) >> 2;   // float4-group index base (1 group = 4 priors)

  __shared__ float s_a[4]; __shared__ float s_b[4]; __shared__ int s_c[4];
  __shared__ float s_v[4]; __shared__ int s_i[4];

  float ce = 0.f, lloc = 0.f; int npos = 0;
  float bestV = -1.f; int bestI = 0;

  if (lab == 0) {
    #pragma unroll
    for (int j = 0; j < CPRI / (4 * K1T); ++j) {
      int q = qbase + j * K1T + t;
      float4 x = cp4[3 * q + 0];
      float4 y = cp4[3 * q + 1];
      float4 z = cp4[3 * q + 2];
      ce += lse3(x.x, x.y, x.z) - x.x;
      ce += lse3(x.w, y.x, y.y) - x.w;
      ce += lse3(y.z, y.w, z.x) - y.z;
      ce += lse3(z.y, z.z, z.w) - z.y;
    }
  } else {
    const float m_c = (t0 + t1) * 0.5f;
    const float m_l = t1 - t0;
    const float2* __restrict__ lp2 = (const float2*)loc_pred;
    float4* __restrict__ lcrow4 = (float4*)(lc + (size_t)b * Dn);
    #pragma unroll
    for (int j = 0; j < CPRI / (4 * K1T); ++j) {
      int q = qbase + j * K1T + t;
      float4 x = cp4[3 * q + 0];
      float4 y = cp4[3 * q + 1];
      float4 z = cp4[3 * q + 2];
      float4 bA = bar4[2 * q + 0];
      float4 bB = bar4[2 * q + 1];
      float cc[12] = {x.x, x.y, x.z, x.w, y.x, y.y, y.z, y.w, z.x, z.y, z.z, z.w};
      float bb[8]  = {bA.x, bA.y, bA.z, bA.w, bB.x, bB.y, bB.z, bB.w};
      float outv[4];
      #pragma unroll
      for (int i = 0; i < 4; ++i) {
        float d_c = bb[2 * i], d_l = bb[2 * i + 1];
        float d_s = d_c - d_l * 0.5f;
        float d_e = d_c + d_l * 0.5f;
        float inter = fmaxf(fminf(t1, d_e) - fmaxf(t0, d_s), 0.f);
        float uni = (t1 - t0) + (d_e - d_s) - inter;
        float ov  = inter / uni;
        float c0 = cc[3 * i];
        float lse = lse3(cc[3 * i], cc[3 * i + 1], cc[3 * i + 2]);
        int p = 4 * q + i;
        if (ov > bestV) { bestV = ov; bestI = p; }
        if (ov >= 0.5f) {
          npos++;
          float cl = (lab == 1) ? cc[3 * i + 1] : cc[3 * i + 2];
          ce += lse - cl;
          float2 lp = lp2[(size_t)b * Dn + p];
          float pd0 = lp.x - (m_c - d_c) / d_l;
          float pd1 = lp.y - __logf(m_l / d_l);
          lloc += sl1f(pd0) + sl1f(pd1);
          outv[i] = 0.f;
        } else {
          outv[i] = lse - c0;
        }
      }
      lcrow4[q] = make_float4(outv[0], outv[1], outv[2], outv[3]);
    }
  }

  // wave butterfly reduce (width 64, always in-range)
  #pragma unroll
  for (int off = 1; off < 64; off <<= 1) {
    ce   += __shfl_xor(ce, off);
    lloc += __shfl_xor(lloc, off);
    npos += __shfl_xor(npos, off);
    float v  = __shfl_xor(bestV, off);
    int   i2 = __shfl_xor(bestI, off);
    if (v > bestV || (v == bestV && i2 < bestI)) { bestV = v; bestI = i2; }
  }
  const int w = t >> 6;
  if ((t & 63) == 0) { s_a[w] = ce; s_b[w] = lloc; s_c[w] = npos; s_v[w] = bestV; s_i[w] = bestI; }
  __syncthreads();
  if (t == 0) {
    float Ce = s_a[0], Ll = s_b[0]; int Np = s_c[0];
    float Bv = s_v[0]; int Bi = s_i[0];
    for (int k = 1; k < 4; ++k) {
      Ce += s_a[k]; Ll += s_b[k]; Np += s_c[k];
      if (s_v[k] > Bv || (s_v[k] == Bv && s_i[k] < Bi)) { Bv = s_v[k]; Bi = s_i[k]; }
    }
    int pidx = b * CHUNKS + c;
    pce[pidx] = Ce; plloc[pidx] = Ll; pnpos[pidx] = Np; pbv[pidx] = Bv; pbi[pidx] = Bi;
  }
}

// ============================ K2: per-row select ============================
__global__ __launch_bounds__(BS) void multiloss_select(
    const float* __restrict__ loc_pred, const float* __restrict__ conf_pred,
    const float* __restrict__ targets, const float* __restrict__ default_bar,
    const float* __restrict__ lc,
    const float* __restrict__ pce, const float* __restrict__ plloc,
    const int* __restrict__ pnpos, const float* __restrict__ pbv, const int* __restrict__ pbi,
    double* __restrict__ rloc, double* __restrict__ rconf, double* __restrict__ rnp)
{
  __shared__ float    s_lc[Dn];        // 64 KB
  __shared__ int      s_hist[2048];    // 8 KB
  __shared__ double   s_dred[BS];      // 4 KB
  __shared__ unsigned s_wt[8];
  __shared__ unsigned s_sel[2];
  __shared__ double   s_sc[2];
  __shared__ int      s_np;

  const int b = blockIdx.x;
  const int t = threadIdx.x;
  const int lab = (int)targets[b * 3 + 2];

  if (lab == 0) {
    if (t == 0) {
      double ce = (double)pce[4 * b] + (double)pce[4 * b + 1]
                + (double)pce[4 * b + 2] + (double)pce[4 * b + 3];
      rloc[b] = 0.0; rconf[b] = ce; rnp[b] = (double)Dn;
    }
    return;
  }

  // load lc row into LDS (float4)
  const float4* lcr = (const float4*)(lc + (size_t)b * Dn);
  float4* sl4 = (float4*)s_lc;
  #pragma unroll
  for (int j = 0; j < Dn / 4 / BS; ++j) sl4[j * BS + t] = lcr[j * BS + t];
  __syncthreads();

  if (t == 0) {
    const float t0 = targets[b * 3 + 0];
    const float t1 = targets[b * 3 + 1];
    double ce = 0.0, ll = 0.0; int np = 0;
    float bV = -1.f; int bI = 0;
    for (int k = 0; k < 4; ++k) {
      int pi = 4 * b + k;
      ce += (double)pce[pi]; ll += (double)plloc[pi]; np += pnpos[pi];
      float v = pbv[pi]; int i2 = pbi[pi];
      if (v > bV || (v == bV && i2 < bI)) { bV = v; bI = i2; }
    }
    if (bV < 0.5f) {
      int d = bI;
      const float* cp = conf_pred + (size_t)b * Dn * 3 + (size_t)d * 3;
      float c0 = cp[0], c1 = cp[1], c2 = cp[2];
      float lse = lse3(c0, c1, c2);
      float cl = (lab == 1) ? c1 : c2;
      ce += (double)(lse - cl);
      float2 db = ((const float2*)default_bar)[d];
      float2 lp = ((const float2*)loc_pred)[(size_t)b * Dn + d];
      float m_c = (t0 + t1) * 0.5f, m_l = t1 - t0;
      float pd0 = lp.x - (m_c - db.x) / db.y;
      float pd1 = lp.y - __logf(m_l / db.y);
      ll += (double)(sl1f(pd0) + sl1f(pd1));
      np += 1;
      s_lc[d] = 0.f;   // forced positive leaves the negative pool
    }
    s_sc[0] = ce; s_sc[1] = ll; s_np = np;
  }
  __syncthreads();
  const int np = s_np;
  const int k = min(3 * np, Dn - 1);

  // ---- radix select: k-th largest of s_lc ----
  unsigned prefix = 0;
  int K = k;
  const int lane = t & 63, w = t >> 6;
  for (int r = 0; r < 3; ++r) {
    for (int i = t; i < 2048; i += BS) s_hist[i] = 0;
    __syncthreads();
    for (int d = t; d < Dn; d += BS) {
      unsigned u = __float_as_uint(s_lc[d]);
      bool ok = (r == 0) || (r == 1 ? ((u >> 21) == prefix) : ((u >> 10) == prefix));
      if (ok) {
        unsigned bin = (r == 0) ? (u >> 21)
                     : (r == 1) ? ((u >> 10) & 0x7FFu)
                                : (u & 0x3FFu);
        atomicAdd(&s_hist[bin], 1);
      }
    }
    __syncthreads();
    const int nb  = (r == 2) ? 1024 : 2048;
    const int per = nb / BS;              // 2 or 4
    unsigned psum = 0;
    const int basebin = t * per;
    for (int j = 0; j < per; ++j) psum += (unsigned)s_hist[basebin + j];
    // wave-level inclusive suffix scan
    unsigned incl = psum;
    #pragma unroll
    for (int off = 1; off < 64; off <<= 1) {
      unsigned v = __shfl_down(incl, off, 64);
      if (lane + off < 64) incl += v;
    }
    if (lane == 0) s_wt[w] = incl;
    __syncthreads();
    unsigned aboveW = 0;
    for (int w2 = w + 1; w2 < 8; ++w2) aboveW += s_wt[w2];
    const unsigned above = aboveW + (incl - psum);   // strict suffix
    if (above < (unsigned)K && (unsigned)K <= above + psum) {
      unsigned cum = above;
      int found = 0;
      for (int j = per - 1; j >= 0; --j) {
        unsigned cnt = (unsigned)s_hist[basebin + j];
        if (cum + cnt >= (unsigned)K) { found = j; break; }
        cum += cnt;
      }
      s_sel[0] = (unsigned)(basebin + found);
      s_sel[1] = cum;
    }
    __syncthreads();
    unsigned selBin = s_sel[0];
    K -= (int)s_sel[1];
    prefix = (r == 0) ? selBin
           : (r == 1) ? ((prefix << 11) | selBin)
                      : ((prefix << 10) | selBin);
    __syncthreads();
  }
  const unsigned tb = prefix;

  // ---- final: sum of strictly-greater + boundary ties ----
  float    ssum = 0.f;
  unsigned scnt = 0;
  for (int d = t; d < Dn; d += BS) {
    float v = s_lc[d];
    if (__float_as_uint(v) > tb) { ssum += v; scnt++; }
  }
  double S = blockReduceAddD((double)ssum, s_dred);
  double C = blockReduceAddD((double)scnt, s_dred);

  if (t == 0) {
    double tval = (double)__uint_as_float(tb);
    double topk = S + ((double)k - C) * tval;
    rloc[b]  = s_sc[1];
    rconf[b] = s_sc[0] + topk;
    rnp[b]   = (double)np;
  }
}

// ============================ fallback mono kernel (proven R1) ============================
__global__ __launch_bounds__(BS) void multiloss_mono(
    const float* __restrict__ loc_pred, const float* __restrict__ conf_pred,
    const float* __restrict__ targets, const float* __restrict__ default_bar,
    double* __restrict__ rloc, double* __restrict__ rconf, double* __restrict__ rnp)
{
  __shared__ float    s_lc[Dn];
  __shared__ int      s_hist[2048];
  __shared__ unsigned s_scan[BS];
  __shared__ double   s_dred[BS];
  __shared__ unsigned s_sel[2];
  __shared__ double   s_corr[2];
  __shared__ int      s_np;

  const int b = blockIdx.x;
  const int t = threadIdx.x;

  const float t0  = targets[b * 3 + 0];
  const float t1  = targets[b * 3 + 1];
  const int   lab = (int)targets[b * 3 + 2];

  const float* __restrict__ cpb = conf_pred + (size_t)b * Dn * 3;

  if (lab == 0) {
    float ce = 0.f;
    for (int d = t; d < Dn; d += BS) {
      const float* cp = cpb + d * 3;
      ce += lse3(cp[0], cp[1], cp[2]) - cp[0];
    }
    double tot = blockReduceAddD((double)ce, s_dred);
    if (t == 0) { rloc[b] = 0.0; rconf[b] = tot; rnp[b] = (double)Dn; }
    return;
  }

  const float m_c = (t0 + t1) * 0.5f;
  const float m_l = t1 - t0;

  float bestV = -1.f; int bestI = 0;
  int   nposL = 0;
  float cePosL = 0.f;
  float llocL  = 0.f;

  for (int d = t; d < Dn; d += BS) {
    float2 db = ((const float2*)default_bar)[d];
    float d_c = db.x, d_l = db.y;
    float d_s = d_c - d_l * 0.5f;
    float d_e = d_c + d_l * 0.5f;
    float inter = fmaxf(fminf(t1, d_e) - fmaxf(t0, d_s), 0.f);
    float uni = (t1 - t0) + (d_e - d_s) - inter;
    float ov  = inter / uni;

    const float* cp = cpb + d * 3;
    float c0 = cp[0];
    float lse = lse3(cp[0], cp[1], cp[2]);

    if (ov > bestV) { bestV = ov; bestI = d; }

    float lcv;
    if (ov >= 0.5f) {
      nposL++;
      float cl = (lab == 1) ? cp[1] : cp[2];
      cePosL += lse - cl;
      float2 lp = ((const float2*)loc_pred)[(size_t)b * Dn + d];
      float pd0 = lp.x - (m_c - d_c) / d_l;
      float pd1 = lp.y - __logf(m_l / d_l);
      llocL += sl1f(pd0) + sl1f(pd1);
      lcv = 0.f;
    } else {
      lcv = lse - c0;
    }
    s_lc[d] = lcv;
  }

  float* sv = (float*)s_hist;
  int*   si = (int*)(s_hist + BS);
  sv[t] = bestV; si[t] = bestI;
  __syncthreads();
  for (int off = BS >> 1; off > 0; off >>= 1) {
    if (t < off) {
      float v2 = sv[t + off]; int i2 = si[t + off];
      if (v2 > sv[t] || (v2 == sv[t] && i2 < si[t])) { sv[t] = v2; si[t] = i2; }
    }
    __syncthreads();
  }
  float bV = sv[0]; int bI = si[0];
  __syncthreads();

  double nposTot  = blockReduceAddD((double)nposL, s_dred);
  double cePosTot = blockReduceAddD((double)cePosL, s_dred);
  double llocTot  = blockReduceAddD((double)llocL, s_dred);
  int num_pos = (int)(nposTot + 0.5);

  if (t == 0) {
    double cc = 0.0, lcor = 0.0; int np2 = num_pos;
    if (bV < 0.5f) {
      int d = bI;
      const float* cp = cpb + d * 3;
      float lse = lse3(cp[0], cp[1], cp[2]);
      float cl = (lab == 1) ? cp[1] : cp[2];
      cc = (double)(lse - cl);
      float2 db = ((const float2*)default_bar)[d];
      float2 lp = ((const float2*)loc_pred)[(size_t)b * Dn + d];
      float pd0 = lp.x - (m_c - db.x) / db.y;
      float pd1 = lp.y - __logf(m_l / db.y);
      lcor = (double)(sl1f(pd0) + sl1f(pd1));
      np2 += 1;
      s_lc[d] = 0.f;
    }
    s_corr[0] = cc; s_corr[1] = lcor; s_np = np2;
  }
  __syncthreads();
  int np = s_np;
  int k  = min(3 * np, Dn - 1);

  unsigned prefix = 0;
  int K = k;
  for (int r = 0; r < 3; ++r) {
    for (int i = t; i < 2048; i += BS) s_hist[i] = 0;
    __syncthreads();
    for (int d = t; d < Dn; d += BS) {
      unsigned u = __float_as_uint(s_lc[d]);
      bool ok = (r == 0) || (r == 1 ? ((u >> 21) == prefix) : ((u >> 10) == prefix));
      if (ok) {
        unsigned bin = (r == 0) ? (u >> 21)
                     : (r == 1) ? ((u >> 10) & 0x7FFu)
                                : (u & 0x3FFu);
        atomicAdd(&s_hist[bin], 1);
      }
    }
    __syncthreads();
    int nb  = (r == 2) ? 1024 : 2048;
    int per = nb / BS;
    unsigned psum = 0;
    for (int j = 0; j < per; ++j) psum += (unsigned)s_hist[t * per + j];
    s_scan[t] = psum;
    __syncthreads();
    for (int off = 1; off < BS; off <<= 1) {
      unsigned v = (t + off < BS) ? s_scan[t + off] : 0u;
      __syncthreads();
      s_scan[t] += v;
      __syncthreads();
    }
    unsigned above = (t < BS - 1) ? s_scan[t + 1] : 0u;
    if (above < (unsigned)K && (unsigned)K <= above + psum) {
      unsigned cum = above;
      int found = 0;
      for (int j = per - 1; j >= 0; --j) {
        unsigned c = (unsigned)s_hist[t * per + j];
        if (cum + c >= (unsigned)K) { found = j; break; }
        cum += c;
      }
      s_sel[0] = (unsigned)(t * per + found);
      s_sel[1] = cum;
    }
    __syncthreads();
    unsigned selBin = s_sel[0];
    K -= (int)s_sel[1];
    prefix = (r == 0) ? selBin
           : (r == 1) ? ((prefix << 11) | selBin)
                      : ((prefix << 10) | selBin);
    __syncthreads();
  }
  const unsigned tb = prefix;

  float    ssum = 0.f;
  unsigned scnt = 0;
  for (int d = t; d < Dn; d += BS) {
    float v = s_lc[d];
    if (__float_as_uint(v) > tb) { ssum += v; scnt++; }
  }
  double S = blockReduceAddD((double)ssum, s_dred);
  double C = blockReduceAddD((double)scnt, s_dred);

  if (t == 0) {
    double tval = (double)__uint_as_float(tb);
    double topk = S + ((double)k - C) * tval;
    rloc[b]  = llocTot + s_corr[1];
    rconf[b] = cePosTot + s_corr[0] + topk;
    rnp[b]   = (double)s_np;
  }
}

// ============================ K3: final reduction ============================
__global__ __launch_bounds__(512) void multiloss_final(
    const double* __restrict__ rloc, const double* __restrict__ rconf,
    const double* __restrict__ rnp, float* __restrict__ out)
{
  __shared__ double s1[512], s2[512], s3[512];
  int t = threadIdx.x;
  s1[t] = rloc[t];
  s2[t] = rconf[t];
  s3[t] = rnp[t];
  __syncthreads();
  for (int off = 256; off > 0; off >>= 1) {
    if (t < off) { s1[t] += s1[t + off]; s2[t] += s2[t + off]; s3[t] += s3[t + off]; }
    __syncthreads();
  }
  if (t == 0) {
    double N = s3[0];
    out[0] = (float)(s1[0] / N);
    out[1] = (float)(s2[0] / N);
  }
}

extern "C" void kernel_launch(void* const* d_in, const int* in_sizes, int n_in,
                              void* d_out, int out_size, void* d_ws, size_t ws_size,
                              hipStream_t stream) {
  const float* loc_pred    = (const float*)d_in[0];
  const float* conf_pred   = (const float*)d_in[1];
  const float* targets     = (const float*)d_in[2];
  const float* default_bar = (const float*)d_in[3];
  float* out = (float*)d_out;
  char* ws = (char*)d_ws;

  constexpr size_t LC_BYTES = (size_t)Bn * Dn * sizeof(float);   // 32 MB
  constexpr size_t P_CNT = (size_t)Bn * CHUNKS;
  size_t off = LC_BYTES;
  float*  pce   = (float*)(ws + off); off += P_CNT * 4;
  float*  plloc = (float*)(ws + off); off += P_CNT * 4;
  int*    pnpos = (int*)(ws + off);   off += P_CNT * 4;
  float*  pbv   = (float*)(ws + off); off += P_CNT * 4;
  int*    pbi   = (int*)(ws + off);   off += P_CNT * 4;
  double* rloc  = (double*)(ws + off); off += Bn * 8;
  double* rconf = (double*)(ws + off); off += Bn * 8;
  double* rnp   = (double*)(ws + off); off += Bn * 8;
  const size_t NEED = off;

  if (ws_size >= NEED) {
    hipLaunchKernelGGL(multiloss_stream, dim3(Bn * CHUNKS), dim3(K1T), 0, stream,
                       loc_pred, conf_pred, targets, default_bar,
                       (float*)ws, pce, plloc, pnpos, pbv, pbi);
    hipLaunchKernelGGL(multiloss_select, dim3(Bn), dim3(BS), 0, stream,
                       loc_pred, conf_pred, targets, default_bar,
                       (const float*)ws, pce, plloc, pnpos, pbv, pbi,
                       rloc, rconf, rnp);
    hipLaunchKernelGGL(multiloss_final, dim3(1), dim3(512), 0, stream,
                       rloc, rconf, rnp, out);
  } else {
    double* mloc  = (double*)ws;
    double* mconf = mloc + Bn;
    double* mnp   = mconf + Bn;
    hipLaunchKernelGGL(multiloss_mono, dim3(Bn), dim3(BS), 0, stream,
                       loc_pred, conf_pred, targets, default_bar, mloc, mconf, mnp);
    hipLaunchKernelGGL(multiloss_final, dim3(1), dim3(512), 0, stream,
                       mloc, mconf, mnp, out);
  }
}